// Round 10
// baseline (221.709 us; speedup 1.0000x reference)
//
#include <hip/hip_runtime.h>

typedef __attribute__((ext_vector_type(8))) short short8;
typedef __attribute__((ext_vector_type(4))) float f32x4;

__device__ __forceinline__ unsigned short bf16rne(float f) {
    unsigned u = __float_as_uint(f);
    u += 0x7FFFu + ((u >> 16) & 1u);
    return (unsigned short)(u >> 16);
}
__device__ __forceinline__ float bf16dec(unsigned short h) {
    return __uint_as_float((unsigned)h << 16);
}
__device__ __forceinline__ unsigned cvtpk2(float lo, float hi) {
    unsigned r;
    asm("v_cvt_pk_bf16_f32 %0, %1, %2" : "=v"(r) : "v"(lo), "v"(hi));
    return r;
}
__device__ __forceinline__ unsigned short cvt1(float f) {
    return (unsigned short)cvtpk2(f, f);
}

extern __shared__ char smem[];

// ================= v9: intra-wave softmax, barrier-light main loop =================
// Wave tile for the offset GEMM: 16 N-columns = 4 cg (=ws4*4..+3) x 4 groups j at
// one tap k. Coupled softmax logits -> 4 consecutive lanes -> dpp quad-perm sum
// (exact f32, no LDS, no barrier). Per-column K-window enforced by exec-masked
// per-lane B loads from a flat bf16 weight copy (invalid lanes contribute 0).
// Main conv: SX in kk2' = k*16+cg order; one K-tile completes per 2 its ->
// barrier every 2 its (5 total), double-buffered SX.
//
// LDS (81280 B -> 2 blocks/CU = 4 waves/SIMD):
//   IMC   [32 px][584] bf16 @0      (37376 B)  im2col (kk = c*9 + tap)
//   PATCH [64 ch][12][16]   @37376  (25344 B)  bf16 halo-4 patch, stride 198 sh
//   SX    [4 j][32 px][72]  @62720  (18560 B)  j-stride 2320 sh; [buf 2][16 cg]
//   OTB alias @37376 (epilogue only)

#define IMC9_OFF   0
#define PATCH9_OFF 37376
#define SX9_OFF    62720
#define LDS_V9     81280
#define OTB9_OFF   37376

#define LOG2E 1.4426950408889634f

#define PW2_U32   124416    // 1728 rows x 72 u32 (bf16 copy of woff, row-major 144)
#define PWM_U32   5120      // 4 j_o x 5 kt2 x 64 lanes x 4 u32, kk2' = k*16+cg order
#define WS_NEEDED ((size_t)(PW2_U32 + PWM_U32) * 4)

__global__ __launch_bounds__(256)
void pack_weights(const float* __restrict__ wmain,
                  const float* __restrict__ woff,
                  unsigned* __restrict__ pw)
{
    int idx = blockIdx.x * 256 + threadIdx.x;
    if (idx < PW2_U32) {
        int och = idx / 72, c2 = (idx - och * 72) * 2;
        float v0 = woff[(size_t)och * 144 + c2];
        float v1 = woff[(size_t)och * 144 + c2 + 1];
        pw[idx] = (unsigned)bf16rne(v0) | ((unsigned)bf16rne(v1) << 16);
    } else if (idx < PW2_U32 + PWM_U32) {
        int m    = idx - PW2_U32;
        int j2   = m & 3;
        int lane = (m >> 2) & 63;
        int rest = m >> 8;                 // j_o*5 + kt2
        int j_o  = rest / 5, kt2 = rest - j_o * 5;
        int o    = j_o * 16 + (lane & 15);
        int kk2  = kt2 * 32 + (lane >> 4) * 8 + j2 * 2;
        float v0 = 0.f, v1 = 0.f;
        if (kk2 < 144)     v0 = wmain[(size_t)o * 144 + (kk2 & 15) * 9 + (kk2 >> 4)];
        if (kk2 + 1 < 144) v1 = wmain[(size_t)o * 144 + ((kk2 + 1) & 15) * 9 + ((kk2 + 1) >> 4)];
        pw[idx] = (unsigned)bf16rne(v0) | ((unsigned)bf16rne(v1) << 16);
    }
}

__global__ __launch_bounds__(512, 4)
void deform_v9(const float* __restrict__ inps,
               const float* __restrict__ bmain,
               const float* __restrict__ boff,
               const unsigned short* __restrict__ pw2,
               const unsigned short* __restrict__ pwm,
               float* __restrict__ out)
{
    unsigned short* IMC   = (unsigned short*)(smem + IMC9_OFF);
    unsigned short* PATCH = (unsigned short*)(smem + PATCH9_OFF);
    unsigned short* SX    = (unsigned short*)(smem + SX9_OFF);
    float*          OTB   = (float*)(smem + OTB9_OFF);

    const int tid  = threadIdx.x;
    const int lane = tid & 63;
    const int wv   = __builtin_amdgcn_readfirstlane(tid >> 6);  // 0..7
    const int ws4  = wv & 3;       // cg-block for sampling; o-group for main conv
    const int mtw  = wv >> 2;      // m-tile half
    const int slot = lane & 15;
    const int q    = lane >> 4;

    const int j_s  = slot & 3;     // group of this lane's sampling column
    const int cgi  = slot >> 2;
    const int cg_s = ws4 * 4 + cgi;        // channel-within-group
    const int c_s  = j_s * 16 + cg_s;      // absolute channel

    const int b    = blockIdx.x >> 7;
    const int tile = blockIdx.x & 127;
    const int ty0  = (tile >> 3) << 2;     // 16 y-tiles of 4
    const int tx0  = (tile & 7) << 3;      // 8 x-tiles of 8

    const float* inb = inps + (size_t)b * 262144;

    // ---- phase 1: PATCH bf16 [64 ch][12 y][16 x] halo 4, zero OOB ----
    for (int e = tid; e < 12288; e += 512) {
        int c = e / 192, rem = e - c * 192;
        int y = rem >> 4, x = rem & 15;
        int gy = ty0 + y - 4, gx = tx0 + x - 4;
        float v = 0.f;
        if ((unsigned)gy < 64u && (unsigned)gx < 64u)
            v = inb[(c * 64 + gy) * 64 + gx];
        PATCH[c * 198 + rem] = cvt1(v);
    }
    __syncthreads();

    // ---- phase 2: im2col IMC[px][kk], kk = c*9 + ky*3 + kx ----
    {
        const int px  = tid >> 4;          // 0..31
        const int sub = tid & 15;
        const int pyr = px >> 3, pxx = px & 7;
        unsigned* dst = (unsigned*)(IMC + px * 584);
        #pragma unroll 3
        for (int i = 0; i < 18; ++i) {
            int u  = i * 16 + sub;
            int kk = u * 2;
            int c0 = kk / 9,        r0 = kk - c0 * 9;
            int c1 = (kk + 1) / 9,  r1 = (kk + 1) - c1 * 9;
            unsigned short a  = PATCH[c0 * 198 + (pyr + r0 / 3 + 3) * 16 + pxx + r0 % 3 + 3];
            unsigned short bb = PATCH[c1 * 198 + (pyr + r1 / 3 + 3) * 16 + pxx + r1 % 3 + 3];
            dst[u] = (unsigned)a | ((unsigned)bb << 16);
        }
    }
    __syncthreads();

    // per-comp window constants (independent of k: c*9+k never crosses a 432 line)
    int dbs0, dbs1, dbs2;
    {
        int g0 = (0 * 576 + c_s * 9) / 432;
        int g1 = (1 * 576 + c_s * 9) / 432;
        int g2 = (2 * 576 + c_s * 9) / 432;
        dbs0 = q * 8 - g0 * 144;
        dbs1 = q * 8 - g1 * 144;
        dbs2 = q * 8 - g2 * 144;
    }

    f32x4 aco = {0.f, 0.f, 0.f, 0.f};
    auto pair_mfma = [&](int kt2) {
        const short8 bfr = ((const short8*)pwm)[(ws4 * 5 + kt2) * 64 + lane];
        const short8 a8  = *(const short8*)(SX + ws4 * 2320 + (mtw * 16 + slot) * 72
                                            + (kt2 & 1) * 32 + q * 8);
        aco = __builtin_amdgcn_mfma_f32_16x16x32_bf16(a8, bfr, aco, 0, 0, 0);
    };

    const short8* ap = (const short8*)(smem + IMC9_OFF) + (mtw * 16 + slot) * 73 + q;

    // ---- phase 3: tap loop, k = 0..8 ----
    for (int k = 0; k < 9; ++k) {
        const int och_s = c_s * 9 + k;
        const unsigned short* rpa0 = pw2 + och_s * 144 + dbs0;
        const unsigned short* rpa1 = pw2 + (576 * 1 + och_s) * 144 + dbs1;
        const unsigned short* rpa2 = pw2 + (576 * 2 + och_s) * 144 + dbs2;

        f32x4 aD = {0.f,0.f,0.f,0.f};
        f32x4 aX = {0.f,0.f,0.f,0.f};
        f32x4 aM = {0.f,0.f,0.f,0.f};

        #pragma unroll
        for (int ktg = 0; ktg < 18; ++ktg) {
            const short8 af = ap[ktg * 4];
            if (ktg <= 8) {                       // comp 0 union: kk [0,288)
                short8 bfr = {0,0,0,0,0,0,0,0};
                if ((unsigned)(ktg * 32 + dbs0) < 144u)
                    bfr = *(const short8*)(rpa0 + ktg * 32);
                aD = __builtin_amdgcn_mfma_f32_16x16x32_bf16(af, bfr, aD, 0, 0, 0);
            }
            if (ktg >= 4 && ktg <= 13) {          // comp 1 union: kk [144,432)
                short8 bfr = {0,0,0,0,0,0,0,0};
                if ((unsigned)(ktg * 32 + dbs1) < 144u)
                    bfr = *(const short8*)(rpa1 + ktg * 32);
                aX = __builtin_amdgcn_mfma_f32_16x16x32_bf16(af, bfr, aX, 0, 0, 0);
            }
            if (ktg >= 9) {                       // comp 2 union: kk [288,576)
                short8 bfr = {0,0,0,0,0,0,0,0};
                if ((unsigned)(ktg * 32 + dbs2) < 144u)
                    bfr = *(const short8*)(rpa2 + ktg * 32);
                aM = __builtin_amdgcn_mfma_f32_16x16x32_bf16(af, bfr, aM, 0, 0, 0);
            }
        }
        {
            const float b0 = boff[och_s];
            const float b1 = boff[576 + och_s];
            const float b2 = boff[1152 + och_s];
            #pragma unroll
            for (int i = 0; i < 4; ++i) { aD[i] += b0; aX[i] += b1; aM[i] += b2; }
        }

        // ---- softmax: exact f32, intra-wave quad reduce (lanes slot = cgi*4 + j) ----
        float er[4];
        #pragma unroll
        for (int r = 0; r < 4; ++r) {
            float e  = exp2f(aM[r] * LOG2E);
            float e1 = __int_as_float(__builtin_amdgcn_mov_dpp(
                           __float_as_int(e), 0xB1, 0xF, 0xF, true));   // quad [1,0,3,2]
            float s2 = e + e1;
            float s3 = __int_as_float(__builtin_amdgcn_mov_dpp(
                           __float_as_int(s2), 0x4E, 0xF, 0xF, true));  // quad [2,3,0,1]
            er[r] = e * __builtin_amdgcn_rcpf(s2 + s3);                 // mask
        }

        // ---- sampling (LDS patch fast path; global fallback) ----
        const int kyk = k / 3, kxk = k - kyk * 3;
        const float fyk = (float)(ty0 + kyk - 1);
        const float fxk = (float)(tx0 + kxk - 1);
        const float* inc = inb + c_s * 4096;
        const int pbase = c_s * 198;
        const int sxb = j_s * 2320 + ((k >> 1) & 1) * 32 + (k & 1) * 16 + cg_s;

        #pragma unroll
        for (int r = 0; r < 4; ++r) {
            const int pxr = mtw * 16 + q * 4 + r;
            const int pyr = pxr >> 3, pxx = pxr & 7;

            float pyf = fyk + (float)pyr + aD[r];
            float pxf = fxk + (float)pxx + aX[r];
            float y0f = floorf(pyf), x0f = floorf(pxf);
            float wy = pyf - y0f, wx = pxf - x0f;
            int iy0 = (int)y0f, ix0 = (int)x0f;

            int ly0 = iy0 - ty0 + 4;
            int lx0 = ix0 - tx0 + 4;
            float v;
            if ((unsigned)ly0 < 11u && (unsigned)lx0 < 15u) {
                const int a = pbase + ly0 * 16 + lx0;
                float p00 = bf16dec(PATCH[a]),      p01 = bf16dec(PATCH[a + 1]);
                float p10 = bf16dec(PATCH[a + 16]), p11 = bf16dec(PATCH[a + 17]);
                float top = fmaf(wx, p01 - p00, p00);
                float bot = fmaf(wx, p11 - p10, p10);
                v = fmaf(wy, bot - top, top);
            } else {
                float w00 = (1.f - wy) * (1.f - wx), w01 = (1.f - wy) * wx;
                float w10 = wy * (1.f - wx),         w11 = wy * wx;
                v = 0.f;
                if ((unsigned)iy0 < 64u) {
                    if ((unsigned)ix0 < 64u)       v += w00 * inc[iy0 * 64 + ix0];
                    if ((unsigned)(ix0 + 1) < 64u) v += w01 * inc[iy0 * 64 + ix0 + 1];
                }
                if ((unsigned)(iy0 + 1) < 64u) {
                    if ((unsigned)ix0 < 64u)       v += w10 * inc[(iy0 + 1) * 64 + ix0];
                    if ((unsigned)(ix0 + 1) < 64u) v += w11 * inc[(iy0 + 1) * 64 + ix0 + 1];
                }
            }
            SX[sxb + pxr * 72] = cvt1(v * er[r]);
        }

        // consume one completed main-conv K-tile every 2 taps
        if (k & 1) { __syncthreads(); pair_mfma(k >> 1); }
    }
    __syncthreads();     // k=8 SX writes visible; all PATCH sampling reads done
    pair_mfma(4);        // half-tile: kk2' >= 144 weights are zero-packed

    // ---- epilogue: transpose via OTB (aliases PATCH), coalesced store ----
    {
        const int o = ws4 * 16 + slot;
        const float bo = bmain[o];
        #pragma unroll
        for (int r = 0; r < 4; ++r)
            OTB[o * 33 + mtw * 16 + q * 4 + r] = aco[r] + bo;
    }
    __syncthreads();
    #pragma unroll
    for (int i = 0; i < 4; ++i) {
        int f  = i * 512 + tid;
        int oo = f >> 5, pp = f & 31;
        out[(size_t)(b * 64 + oo) * 4096 + (ty0 + (pp >> 3)) * 64 + (tx0 + (pp & 7))] =
            OTB[oo * 33 + pp];
    }
}

// ======================= v2 fallback (proven; no ws needed) =======================
#define V2IMC_OFF   0
#define V2S_OFF     37376
#define V2LGX_OFF   74752
#define V2LDS_BYTES 78848

__global__ __launch_bounds__(256, 2)
void deform_v2(const float* __restrict__ inps,
               const float* __restrict__ wmain,
               const float* __restrict__ bmain,
               const float* __restrict__ woff,
               const float* __restrict__ boff,
               float* __restrict__ out)
{
    unsigned short* IMC  = (unsigned short*)(smem + V2IMC_OFF);
    unsigned short* SBUF = (unsigned short*)(smem + V2S_OFF);
    unsigned short* LGX  = (unsigned short*)(smem + V2LGX_OFF);
    float* PATCH = (float*)(smem + V2S_OFF);
    float* OTB   = (float*)(smem + V2IMC_OFF);

    const int tid  = threadIdx.x;
    const int lane = tid & 63;
    const int jw   = __builtin_amdgcn_readfirstlane(tid >> 6);
    const int slot = lane & 15;
    const int q    = lane >> 4;

    const int b    = blockIdx.x >> 7;
    const int tile = blockIdx.x & 127;
    const int ty0  = (tile >> 3) << 2;
    const int tx0  = (tile & 7) << 3;

    const float* inb = inps + (size_t)b * 262144;

    for (int e = tid; e < 64 * 60; e += 256) {
        int ch = e / 60, rem = e - ch * 60;
        int iy = rem / 10, ix = rem - iy * 10;
        int gy = ty0 + iy - 1, gx = tx0 + ix - 1;
        float v = 0.f;
        if ((unsigned)gy < 64u && (unsigned)gx < 64u)
            v = inb[(ch * 64 + gy) * 64 + gx];
        PATCH[ch * 61 + rem] = v;
    }
    __syncthreads();
    {
        const int px  = tid >> 3;
        const int sub = tid & 7;
        const int pyr = px >> 3, pxx = px & 7;
        unsigned short* dst = IMC + px * 584;
        for (int i = 0; i < 36; ++i) {
            int kk = sub * 72 + 2 * i;
            float v0, v1;
            { int c = kk / 9, r9 = kk - c * 9, ky = r9 / 3, kx = r9 - ky * 3;
              v0 = PATCH[c * 61 + (pyr + ky) * 10 + (pxx + kx)]; }
            { int k1 = kk + 1; int c = k1 / 9, r9 = k1 - c * 9, ky = r9 / 3, kx = r9 - ky * 3;
              v1 = PATCH[c * 61 + (pyr + ky) * 10 + (pxx + kx)]; }
            *(unsigned*)(dst + kk) = cvtpk2(v0, v1);
        }
    }
    __syncthreads();

    for (int ntg = 0; ntg < 9; ++ntg) {
        f32x4 aD[2] = {{0.f,0.f,0.f,0.f},{0.f,0.f,0.f,0.f}};
        f32x4 aX[2] = {{0.f,0.f,0.f,0.f},{0.f,0.f,0.f,0.f}};
        f32x4 aM[2] = {{0.f,0.f,0.f,0.f},{0.f,0.f,0.f,0.f}};

        auto gemm3 = [&](f32x4* acc, int comp) {
            const int ochb = comp * 576 + jw * 144 + ntg * 16;
            const int g    = ochb / 432;
            const int ktf  = (9 * g) >> 1;
            const int ch0  = g * 18;
            const int och  = ochb + slot;
            #pragma unroll
            for (int kt = 0; kt < 5; ++kt) {
                const int ktg   = ktf + kt;
                const int chunk = ktg * 4 + q;
                short8 bfr;
                if ((unsigned)(chunk - ch0) < 18u) {
                    const float4* wp = (const float4*)(woff + (size_t)och * 144 + (chunk - ch0) * 8);
                    float4 w0 = wp[0], w1 = wp[1];
                    union { unsigned u[4]; short8 s; } cv;
                    cv.u[0] = cvtpk2(w0.x, w0.y); cv.u[1] = cvtpk2(w0.z, w0.w);
                    cv.u[2] = cvtpk2(w1.x, w1.y); cv.u[3] = cvtpk2(w1.z, w1.w);
                    bfr = cv.s;
                } else {
                    bfr = short8{0,0,0,0,0,0,0,0};
                }
                #pragma unroll
                for (int mt = 0; mt < 2; ++mt) {
                    const short8* ap = (const short8*)(smem + V2IMC_OFF +
                                        (mt * 16 + slot) * 1168 + ktg * 64 + q * 16);
                    acc[mt] = __builtin_amdgcn_mfma_f32_16x16x32_bf16(*ap, bfr, acc[mt], 0, 0, 0);
                }
            }
            const float bo = boff[ochb + slot];
            #pragma unroll
            for (int mt = 0; mt < 2; ++mt) {
                acc[mt][0] += bo; acc[mt][1] += bo; acc[mt][2] += bo; acc[mt][3] += bo;
            }
        };
        gemm3(aD, 0); gemm3(aX, 1); gemm3(aM, 2);

        #pragma unroll
        for (int mt = 0; mt < 2; ++mt)
        #pragma unroll
        for (int r = 0; r < 4; ++r) {
            int pxr = mt * 16 + q * 4 + r;
            LGX[(jw * 32 + pxr) * 16 + slot] = bf16rne(aM[mt][r]);
        }
        __syncthreads();

        const int rr  = ntg * 16 + slot;
        const int cg  = rr / 9;
        const int kk9 = rr - cg * 9;
        const int kyk = kk9 / 3, kxk = kk9 - kyk * 3;
        const float* inc = inb + (jw * 16 + cg) * 4096;

        #pragma unroll
        for (int mt = 0; mt < 2; ++mt)
        #pragma unroll
        for (int r = 0; r < 4; ++r) {
            const int pxr = mt * 16 + q * 4 + r;
            const int pyr = pxr >> 3, pxx = pxr & 7;
            float own = aM[mt][r];
            float l0 = (jw == 0) ? own : bf16dec(LGX[(0 * 32 + pxr) * 16 + slot]);
            float l1 = (jw == 1) ? own : bf16dec(LGX[(1 * 32 + pxr) * 16 + slot]);
            float l2 = (jw == 2) ? own : bf16dec(LGX[(2 * 32 + pxr) * 16 + slot]);
            float l3 = (jw == 3) ? own : bf16dec(LGX[(3 * 32 + pxr) * 16 + slot]);
            float m4 = fmaxf(fmaxf(l0, l1), fmaxf(l2, l3));
            float s4 = __expf(l0 - m4) + __expf(l1 - m4) + __expf(l2 - m4) + __expf(l3 - m4);
            float msk = __expf(own - m4) / s4;

            float pyf = (float)(ty0 + pyr + kyk - 1) + aD[mt][r];
            float pxf = (float)(tx0 + pxx + kxk - 1) + aX[mt][r];
            float y0f = floorf(pyf), x0f = floorf(pxf);
            float wy = pyf - y0f, wx = pxf - x0f;
            int iy0 = (int)y0f, ix0 = (int)x0f;
            float w00 = (1.f - wy) * (1.f - wx), w01 = (1.f - wy) * wx;
            float w10 = wy * (1.f - wx),         w11 = wy * wx;
            float v = 0.f;
            if ((unsigned)iy0 < 64u) {
                if ((unsigned)ix0 < 64u)       v += w00 * inc[iy0 * 64 + ix0];
                if ((unsigned)(ix0 + 1) < 64u) v += w01 * inc[iy0 * 64 + ix0 + 1];
            }
            if ((unsigned)(iy0 + 1) < 64u) {
                if ((unsigned)ix0 < 64u)       v += w10 * inc[(iy0 + 1) * 64 + ix0];
                if ((unsigned)(ix0 + 1) < 64u) v += w11 * inc[(iy0 + 1) * 64 + ix0 + 1];
            }
            SBUF[pxr * 584 + jw * 144 + rr] = bf16rne(v * msk);
        }
        __syncthreads();
    }

    {
        f32x4 aco2[2] = {{0.f,0.f,0.f,0.f},{0.f,0.f,0.f,0.f}};
        const int ktf = (9 * jw) >> 1;
        const int ch0 = jw * 18;
        const int o   = jw * 16 + slot;
        #pragma unroll
        for (int kt = 0; kt < 5; ++kt) {
            const int ktg   = ktf + kt;
            const int chunk = ktg * 4 + q;
            short8 bfr;
            if ((unsigned)(chunk - ch0) < 18u) {
                const float4* wp = (const float4*)(wmain + (size_t)o * 144 + (chunk - ch0) * 8);
                float4 w0 = wp[0], w1 = wp[1];
                union { unsigned u[4]; short8 s; } cv;
                cv.u[0] = cvtpk2(w0.x, w0.y); cv.u[1] = cvtpk2(w0.z, w0.w);
                cv.u[2] = cvtpk2(w1.x, w1.y); cv.u[3] = cvtpk2(w1.z, w1.w);
                bfr = cv.s;
            } else {
                bfr = short8{0,0,0,0,0,0,0,0};
            }
            #pragma unroll
            for (int mt = 0; mt < 2; ++mt) {
                const short8* ap = (const short8*)(smem + V2S_OFF +
                                    (mt * 16 + slot) * 1168 + ktg * 64 + q * 16);
                aco2[mt] = __builtin_amdgcn_mfma_f32_16x16x32_bf16(*ap, bfr, aco2[mt], 0, 0, 0);
            }
        }
        const float bo = bmain[o];
        __syncthreads();
        #pragma unroll
        for (int mt = 0; mt < 2; ++mt)
        #pragma unroll
        for (int r = 0; r < 4; ++r)
            OTB[o * 33 + mt * 16 + q * 4 + r] = aco2[mt][r] + bo;
    }
    __syncthreads();
    #pragma unroll
    for (int i = 0; i < 8; ++i) {
        int f  = i * 256 + tid;
        int oo = f >> 5, pp = f & 31;
        out[(size_t)(b * 64 + oo) * 4096 + (ty0 + (pp >> 3)) * 64 + (tx0 + (pp & 7))] =
            OTB[oo * 33 + pp];
    }
}

extern "C" void kernel_launch(void* const* d_in, const int* in_sizes, int n_in,
                              void* d_out, int out_size, void* d_ws, size_t ws_size,
                              hipStream_t stream) {
    const float* inps   = (const float*)d_in[0];
    const float* weight = (const float*)d_in[1];
    const float* bias   = (const float*)d_in[2];
    const float* woff   = (const float*)d_in[3];
    const float* boff   = (const float*)d_in[4];
    float* outp = (float*)d_out;

    if (ws_size >= WS_NEEDED) {
        unsigned* pw = (unsigned*)d_ws;
        pack_weights<<<dim3(507), dim3(256), 0, stream>>>(weight, woff, pw);
        hipFuncSetAttribute((const void*)deform_v9,
                            hipFuncAttributeMaxDynamicSharedMemorySize, LDS_V9);
        deform_v9<<<dim3(1024), dim3(512), LDS_V9, stream>>>(
            inps, bias, boff,
            (const unsigned short*)pw,
            (const unsigned short*)(pw + PW2_U32), outp);
    } else {
        hipFuncSetAttribute((const void*)deform_v2,
                            hipFuncAttributeMaxDynamicSharedMemorySize, V2LDS_BYTES);
        deform_v2<<<dim3(1024), dim3(256), V2LDS_BYTES, stream>>>(
            inps, weight, bias, woff, boff, outp);
    }
}

// Round 11
// 125.742 us; speedup vs baseline: 1.7632x; 1.7632x over previous
//
#include <hip/hip_runtime.h>

typedef __attribute__((ext_vector_type(8))) short short8;
typedef __attribute__((ext_vector_type(4))) float f32x4;

__device__ __forceinline__ unsigned short bf16rne(float f) {
    unsigned u = __float_as_uint(f);
    u += 0x7FFFu + ((u >> 16) & 1u);
    return (unsigned short)(u >> 16);
}
__device__ __forceinline__ float bf16dec(unsigned short h) {
    return __uint_as_float((unsigned)h << 16);
}
__device__ __forceinline__ unsigned cvtpk2(float lo, float hi) {
    unsigned r;
    asm("v_cvt_pk_bf16_f32 %0, %1, %2" : "=v"(r) : "v"(lo), "v"(hi));
    return r;
}
__device__ __forceinline__ unsigned short cvt1(float f) {
    return (unsigned short)cvtpk2(f, f);
}
__device__ __forceinline__ float declo(unsigned u) { return __uint_as_float(u << 16); }
__device__ __forceinline__ float dechi(unsigned u) { return __uint_as_float(u & 0xFFFF0000u); }

extern __shared__ char smem[];

// ============ v10: v8 dataflow, ntg processed in PAIRS (2 indep chains) ============
// 512 thr/block (4 jw x 2 mt), 2 blocks/CU, 4 waves/SIMD (launch_bounds 512,4).
// Pair step: gemm3 x2 ntg (shared A-frag reads), exp x2, LGX writes -> ONE
// barrier -> sampling x2 -> pair_mfma. LGX double-buffered per PAIR (alternating)
// so no trailing barrier (WAR-safe: any wave passing barrier(p+1) implies all
// waves finished pair-p sampling). Barriers: 5 vs v8's 9; 2 indep dep-chains
// between barriers. PATCH halo 3 (offset std ~0.6 px -> fallback P~3e-5).
// SX stride 34 shorts (17-bank step, conflict-free).
//
// LDS (81536 B -> 2 blocks/CU):
//   IMC   [32 px][584] bf16      @0      (37376 B)
//   PATCH [64 ch][10 y][14 x]+1  @37376  (18048 B)  stride 141 sh
//   SX    [4 jw][32 px][34]      @55424  ( 8704 B)
//   LGX   2 x [32 px][2][68]     @64128  (17408 B)
//   OTB alias @37376 (epilogue only)

#define IMC10_OFF   0
#define PATCH10_OFF 37376
#define SX10_OFF    55424
#define LGX10_OFF   64128
#define LDS_V10     81536
#define OTB10_OFF   37376

#define LOG2E 1.4426950408889634f

#define PWOFF_U32  138240
#define PWM_U32    5120
#define WS_NEEDED  ((size_t)(PWOFF_U32 + PWM_U32) * 4)

__global__ __launch_bounds__(256)
void pack_weights(const float* __restrict__ wmain,
                  const float* __restrict__ woff,
                  unsigned* __restrict__ pw)
{
    int idx = blockIdx.x * 256 + threadIdx.x;
    if (idx < PWOFF_U32) {
        int j2   = idx & 3;
        int lane = (idx >> 2) & 63;
        int rest = idx >> 8;              // t*5 + kt
        int kt   = rest % 5;
        int t    = rest / 5;
        int comp = t / 36, r36 = t - comp * 36;
        int jw   = r36 / 9, ntg = r36 - jw * 9;
        int ochb = comp * 576 + jw * 144 + ntg * 16;
        int g    = ochb / 432;
        int ktf  = (9 * g) >> 1;
        int och  = ochb + (lane & 15);
        int ck   = (ktf + kt) * 32 + (lane >> 4) * 8 + j2 * 2 - g * 144;
        float v0 = 0.f, v1 = 0.f;
        if ((unsigned)ck < 144u)       v0 = woff[(size_t)och * 144 + ck];
        if ((unsigned)(ck + 1) < 144u) v1 = woff[(size_t)och * 144 + ck + 1];
        pw[idx] = (unsigned)bf16rne(v0) | ((unsigned)bf16rne(v1) << 16);
    } else if (idx < PWOFF_U32 + PWM_U32) {
        int m    = idx - PWOFF_U32;
        int j2   = m & 3;
        int lane = (m >> 2) & 63;
        int rest = m >> 8;                // jw*5 + pair
        int jw   = rest / 5, pair = rest - jw * 5;
        int och  = jw * 16 + (lane & 15);
        int w0   = pair * 32 + (lane >> 4) * 8 + j2 * 2;
        float v0 = (w0 < 144)     ? wmain[(size_t)och * 144 + w0]     : 0.f;
        float v1 = (w0 + 1 < 144) ? wmain[(size_t)och * 144 + w0 + 1] : 0.f;
        pw[idx] = (unsigned)bf16rne(v0) | ((unsigned)bf16rne(v1) << 16);
    }
}

__global__ __launch_bounds__(512, 4)
void deform_v10(const float* __restrict__ inps,
                const float* __restrict__ bmain,
                const float* __restrict__ boff,
                const unsigned short* __restrict__ pwoff,
                const unsigned short* __restrict__ pwm,
                float* __restrict__ out)
{
    unsigned short* IMC   = (unsigned short*)(smem + IMC10_OFF);
    unsigned short* PATCH = (unsigned short*)(smem + PATCH10_OFF);
    unsigned short* SX    = (unsigned short*)(smem + SX10_OFF);
    unsigned short* LGX   = (unsigned short*)(smem + LGX10_OFF);
    float*          OTB   = (float*)(smem + OTB10_OFF);

    const int tid  = threadIdx.x;
    const int lane = tid & 63;
    const int wv   = __builtin_amdgcn_readfirstlane(tid >> 6);  // 0..7
    const int jw   = wv & 3;
    const int mtw  = wv >> 2;
    const int slot = lane & 15;
    const int q    = lane >> 4;

    const int b    = blockIdx.x >> 7;
    const int tile = blockIdx.x & 127;
    const int ty0  = (tile >> 3) << 2;     // 16 y-tiles of 4
    const int tx0  = (tile & 7) << 3;      // 8 x-tiles of 8

    const float* inb = inps + (size_t)b * 262144;

    // ---- phase 1: PATCH bf16 [64 ch][10 y][14 x] halo 3, zero OOB ----
    for (int e = tid; e < 8960; e += 512) {
        int c = e / 140, rem = e - c * 140;
        int y = rem / 14, x = rem - y * 14;
        int gy = ty0 + y - 3, gx = tx0 + x - 3;
        float v = 0.f;
        if ((unsigned)gy < 64u && (unsigned)gx < 64u)
            v = inb[(c * 64 + gy) * 64 + gx];
        PATCH[c * 141 + y * 14 + x] = cvt1(v);
    }
    __syncthreads();

    // ---- phase 2: im2col IMC[px][kk], kk = c*9 + ky*3 + kx ----
    {
        const int px  = tid >> 4;          // 0..31
        const int sub = tid & 15;
        const int pyr = px >> 3, pxx = px & 7;
        unsigned* dst = (unsigned*)(IMC + px * 584);
        #pragma unroll 3
        for (int i = 0; i < 18; ++i) {
            int u  = i * 16 + sub;
            int kk = u * 2;
            int c0 = kk / 9,        r0 = kk - c0 * 9;
            int c1 = (kk + 1) / 9,  r1 = (kk + 1) - c1 * 9;
            unsigned short a  = PATCH[c0 * 141 + (pyr + r0 / 3 + 2) * 14 + pxx + r0 % 3 + 2];
            unsigned short bb = PATCH[c1 * 141 + (pyr + r1 / 3 + 2) * 14 + pxx + r1 % 3 + 2];
            dst[u] = (unsigned)a | ((unsigned)bb << 16);
        }
    }
    __syncthreads();

    const short8* ap = (const short8*)(smem + IMC10_OFF) + (mtw * 16 + slot) * 73 + q;

    f32x4 aco = {0.f, 0.f, 0.f, 0.f};
    auto pair_mfma = [&](int kt2) {
        const short8 bfr = ((const short8*)pwm)[(jw * 5 + kt2) * 64 + lane];
        const short8 a8  = *(const short8*)(SX + jw * 1088 + (mtw * 16 + slot) * 34 + q * 8);
        aco = __builtin_amdgcn_mfma_f32_16x16x32_bf16(a8, bfr, aco, 0, 0, 0);
    };

    auto gemmpair = [&](int comp, int n0, f32x4& acc0, f32x4& acc1) {
        const int ochb0 = comp * 576 + jw * 144 + n0 * 16;
        const int g     = ochb0 / 432;           // same for n0 and n0+1 (144 | 432)
        const int ktf   = (9 * g) >> 1;
        const short8* wp0 = (const short8*)pwoff + (comp * 36 + jw * 9 + n0) * 320 + lane;
        const short8* wp1 = wp0 + 320;
        short8 b0[5], b1[5];
        #pragma unroll
        for (int kt = 0; kt < 5; ++kt) { b0[kt] = wp0[kt * 64]; b1[kt] = wp1[kt * 64]; }
        #pragma unroll
        for (int kt = 0; kt < 5; ++kt) {
            const short8 af = ap[(ktf + kt) * 4];
            acc0 = __builtin_amdgcn_mfma_f32_16x16x32_bf16(af, b0[kt], acc0, 0, 0, 0);
            acc1 = __builtin_amdgcn_mfma_f32_16x16x32_bf16(af, b1[kt], acc1, 0, 0, 0);
        }
        const float bo0 = boff[ochb0 + slot];
        const float bo1 = boff[ochb0 + 16 + slot];
        #pragma unroll
        for (int i = 0; i < 4; ++i) { acc0[i] += bo0; acc1[i] += bo1; }
    };

    auto gemmsingle = [&](int comp, int n0, f32x4& acc) {
        const int ochb = comp * 576 + jw * 144 + n0 * 16;
        const int g    = ochb / 432;
        const int ktf  = (9 * g) >> 1;
        const short8* wp = (const short8*)pwoff + (comp * 36 + jw * 9 + n0) * 320 + lane;
        short8 bw[5];
        #pragma unroll
        for (int kt = 0; kt < 5; ++kt) bw[kt] = wp[kt * 64];
        #pragma unroll
        for (int kt = 0; kt < 5; ++kt) {
            const short8 af = ap[(ktf + kt) * 4];
            acc = __builtin_amdgcn_mfma_f32_16x16x32_bf16(af, bw[kt], acc, 0, 0, 0);
        }
        const float bo = boff[ochb + slot];
        #pragma unroll
        for (int i = 0; i < 4; ++i) acc[i] += bo;
    };

    auto expwrite = [&](int ntg, const f32x4& aM, float* er, int lgb) {
        #pragma unroll
        for (int r = 0; r < 4; ++r) {
            er[r] = exp2f(aM[r] * LOG2E);
            int pxr = mtw * 16 + q * 4 + r;
            LGX[lgb + pxr * 136 + (ntg & 1) * 68 + slot * 4 + jw] = cvt1(er[r]);
        }
    };

    auto sample4 = [&](int ntg, const f32x4& aD, const f32x4& aX,
                       const float* er, int lgb) {
        const int rr  = ntg * 16 + slot;
        const int cg  = rr / 9;
        const int kk9 = rr - cg * 9;
        const int kyk = kk9 / 3, kxk = kk9 - kyk * 3;
        const int c   = jw * 16 + cg;
        const float* inc = inb + c * 4096;
        const int pbase = c * 141;
        const int par = ntg & 1;
        const float fyk = (float)(ty0 + kyk - 1);
        const float fxk = (float)(tx0 + kxk - 1);

        #pragma unroll
        for (int r = 0; r < 4; ++r) {
            const int pxr = mtw * 16 + q * 4 + r;
            const int pyr = pxr >> 3, pxx = pxr & 7;

            const uint2 lg = *(const uint2*)(LGX + lgb + pxr * 136 + par * 68 + slot * 4);
            const float s4 = declo(lg.x) + dechi(lg.x) + declo(lg.y) + dechi(lg.y);
            const float msk = er[r] * __builtin_amdgcn_rcpf(s4);

            float pyf = fyk + (float)pyr + aD[r];
            float pxf = fxk + (float)pxx + aX[r];
            float y0f = floorf(pyf), x0f = floorf(pxf);
            float wy = pyf - y0f, wx = pxf - x0f;
            int iy0 = (int)y0f, ix0 = (int)x0f;

            int ly0 = iy0 - ty0 + 3;
            int lx0 = ix0 - tx0 + 3;
            float v;
            if ((unsigned)ly0 < 9u && (unsigned)lx0 < 13u) {
                const int a = pbase + ly0 * 14 + lx0;
                float p00 = bf16dec(PATCH[a]),      p01 = bf16dec(PATCH[a + 1]);
                float p10 = bf16dec(PATCH[a + 14]), p11 = bf16dec(PATCH[a + 15]);
                float top = fmaf(wx, p01 - p00, p00);
                float bot = fmaf(wx, p11 - p10, p10);
                v = fmaf(wy, bot - top, top);
            } else {
                float w00 = (1.f - wy) * (1.f - wx), w01 = (1.f - wy) * wx;
                float w10 = wy * (1.f - wx),         w11 = wy * wx;
                v = 0.f;
                if ((unsigned)iy0 < 64u) {
                    if ((unsigned)ix0 < 64u)       v += w00 * inc[iy0 * 64 + ix0];
                    if ((unsigned)(ix0 + 1) < 64u) v += w01 * inc[iy0 * 64 + ix0 + 1];
                }
                if ((unsigned)(iy0 + 1) < 64u) {
                    if ((unsigned)ix0 < 64u)       v += w10 * inc[(iy0 + 1) * 64 + ix0];
                    if ((unsigned)(ix0 + 1) < 64u) v += w11 * inc[(iy0 + 1) * 64 + ix0 + 1];
                }
            }
            SX[jw * 1088 + pxr * 34 + par * 16 + slot] = cvt1(v * msk);
        }
    };

    // ---- phase 3: 4 pairs + tail ----
    for (int p = 0; p < 4; ++p) {
        const int n0  = 2 * p;
        const int lgb = (p & 1) * 4352;

        f32x4 aD0 = {0.f,0.f,0.f,0.f}, aX0 = {0.f,0.f,0.f,0.f}, aM0 = {0.f,0.f,0.f,0.f};
        f32x4 aD1 = {0.f,0.f,0.f,0.f}, aX1 = {0.f,0.f,0.f,0.f}, aM1 = {0.f,0.f,0.f,0.f};
        gemmpair(0, n0, aD0, aD1);
        gemmpair(1, n0, aX0, aX1);
        gemmpair(2, n0, aM0, aM1);

        float er0[4], er1[4];
        expwrite(n0,     aM0, er0, lgb);
        expwrite(n0 + 1, aM1, er1, lgb);
        __syncthreads();

        sample4(n0,     aD0, aX0, er0, lgb);
        sample4(n0 + 1, aD1, aX1, er1, lgb);

        asm volatile("" ::: "memory");
        pair_mfma(p);
        // no trailing barrier: next pair uses the other LGX buffer.
    }
    {   // tail: ntg = 8 (buf 0 safe after barrier of pair 3)
        f32x4 aD = {0.f,0.f,0.f,0.f}, aX = {0.f,0.f,0.f,0.f}, aM = {0.f,0.f,0.f,0.f};
        gemmsingle(0, 8, aD);
        gemmsingle(1, 8, aX);
        gemmsingle(2, 8, aM);
        float er[4];
        expwrite(8, aM, er, 0);
        __syncthreads();
        sample4(8, aD, aX, er, 0);
        asm volatile("" ::: "memory");
        pair_mfma(4);   // par1 half zero-packed in pwm -> contributes 0
    }
    __syncthreads();   // PATCH sampling reads done before OTB overwrite

    // ---- epilogue ----
    {
        const int o = jw * 16 + slot;
        const float bo = bmain[o];
        #pragma unroll
        for (int r = 0; r < 4; ++r)
            OTB[o * 33 + mtw * 16 + q * 4 + r] = aco[r] + bo;
    }
    __syncthreads();
    #pragma unroll
    for (int i = 0; i < 4; ++i) {
        int f  = i * 512 + tid;
        int oo = f >> 5, pp = f & 31;
        out[(size_t)(b * 64 + oo) * 4096 + (ty0 + (pp >> 3)) * 64 + (tx0 + (pp & 7))] =
            OTB[oo * 33 + pp];
    }
}

extern "C" void kernel_launch(void* const* d_in, const int* in_sizes, int n_in,
                              void* d_out, int out_size, void* d_ws, size_t ws_size,
                              hipStream_t stream) {
    const float* inps   = (const float*)d_in[0];
    const float* weight = (const float*)d_in[1];
    const float* bias   = (const float*)d_in[2];
    const float* woff   = (const float*)d_in[3];
    const float* boff   = (const float*)d_in[4];
    float* outp = (float*)d_out;

    unsigned* pw = (unsigned*)d_ws;
    pack_weights<<<dim3(560), dim3(256), 0, stream>>>(weight, woff, pw);
    hipFuncSetAttribute((const void*)deform_v10,
                        hipFuncAttributeMaxDynamicSharedMemorySize, LDS_V10);
    deform_v10<<<dim3(1024), dim3(512), LDS_V10, stream>>>(
        inps, bias, boff,
        (const unsigned short*)pw,
        (const unsigned short*)(pw + PWOFF_U32), outp);
    (void)ws_size; (void)in_sizes; (void)n_in; (void)out_size;
}